// Round 8
// baseline (331.422 us; speedup 1.0000x reference)
//
#include <hip/hip_runtime.h>
#include <hip/hip_bf16.h>

#define D_MODEL  1280
#define D_BOTTLE 64
#define LN_EPS   1e-5f
#define TM       16
#define GP       72     // padded g_lds row stride (bf16 elems)

typedef __attribute__((ext_vector_type(8))) short short8;
typedef __attribute__((ext_vector_type(4))) float floatx4;

static __device__ inline unsigned short f2bf(float f) {
    __hip_bfloat16 h = __float2bfloat16(f);
    return *reinterpret_cast<unsigned short*>(&h);
}
static __device__ inline float bf2f(unsigned short u) {
    unsigned int v = ((unsigned int)u) << 16;
    return __uint_as_float(v);
}

// Prep 1 (elementwise): wg = bf16(wd * gamma)  [64][1280] ; wu_b = bf16(wu) [1280][64]
__global__ void prep_weights(const float* __restrict__ wd, const float* __restrict__ gamma,
                             const float* __restrict__ wu,
                             unsigned short* __restrict__ wg, unsigned short* __restrict__ wu_b) {
    int i = blockIdx.x * blockDim.x + threadIdx.x;
    if (i < D_MODEL * D_BOTTLE) {
        int k = i % D_MODEL;                 // wd is [n][k] row-major
        wg[i]   = f2bf(wd[i] * gamma[k]);
        wu_b[i] = f2bf(wu[i]);
    }
}

// Prep 2 (per-n reductions): colsum[n] = sum_k bf2f(wg[n,k]) ; bd2[n] = b_down[n] + sum_k wd[n,k]*beta[k]
__global__ void prep_reduce(const unsigned short* __restrict__ wg, const float* __restrict__ wd,
                            const float* __restrict__ beta, const float* __restrict__ b_down,
                            float* __restrict__ colsum, float* __restrict__ bd2) {
    const int n = blockIdx.x;           // 0..63
    const int t = threadIdx.x;          // 256 threads
    float cs = 0.f, bb = 0.f;
    for (int k = t; k < D_MODEL; k += 256) {
        cs += bf2f(wg[n * D_MODEL + k]);
        bb += wd[n * D_MODEL + k] * beta[k];
    }
    #pragma unroll
    for (int m = 1; m < 64; m <<= 1) {
        cs += __shfl_xor(cs, m);
        bb += __shfl_xor(bb, m);
    }
    __shared__ float scs[4], sbb[4];
    if ((t & 63) == 0) { scs[t >> 6] = cs; sbb[t >> 6] = bb; }
    __syncthreads();
    if (t == 0) {
        colsum[n] = scs[0] + scs[1] + scs[2] + scs[3];
        bd2[n]    = b_down[n] + sbb[0] + sbb[1] + sbb[2] + sbb[3];
    }
}

__global__ __launch_bounds__(256, 4) void adapter_kernel(
    const float* __restrict__ x,
    const unsigned short* __restrict__ wg, const float* __restrict__ colsum,
    const float* __restrict__ bd2,
    const unsigned short* __restrict__ wu_b, const float* __restrict__ b_up,
    float* __restrict__ out)
{
    __shared__ float s_mean[TM];
    __shared__ float s_rinv[TM];
    __shared__ unsigned short g_lds[TM * GP];   // gelu(down), bf16

    const int tid  = threadIdx.x;
    const int wave = tid >> 6;
    const int lane = tid & 63;
    const int r0   = blockIdx.x * TM;

    // ---------------- Phase 1: row stats only (16 lanes per row, 4 rows per wave) ----------
    {
        const int rloc = wave * 4 + (lane >> 4);
        const int lr   = lane & 15;
        const float* xrow = x + (size_t)(r0 + rloc) * D_MODEL;
        float s = 0.f, sq = 0.f;
        #pragma unroll
        for (int t = 0; t < 20; ++t) {
            float4 v = *reinterpret_cast<const float4*>(xrow + (lr + 16 * t) * 4);
            s  += v.x + v.y + v.z + v.w;
            sq += v.x * v.x + v.y * v.y + v.z * v.z + v.w * v.w;
        }
        #pragma unroll
        for (int m = 1; m < 16; m <<= 1) {
            s  += __shfl_xor(s, m);
            sq += __shfl_xor(sq, m);
        }
        const float mean = s * (1.f / D_MODEL);
        const float var  = sq * (1.f / D_MODEL) - mean * mean;
        if (lr == 0) {
            s_mean[rloc] = mean;
            s_rinv[rloc] = rsqrtf(var + LN_EPS);
        }
    }
    __syncthreads();

    // ---------------- Phase 2: down-proj on RAW x (M=16,N=64,K=1280), wave w -> n-tile w ----
    const int l15   = lane & 15;
    const int khalf = lane >> 4;            // 0..3
    const int n0    = wave * 16;
    const int nn    = n0 + l15;

    floatx4 acc = {0.f, 0.f, 0.f, 0.f};
    {
        const float* arow = x + (size_t)(r0 + l15) * D_MODEL + khalf * 8;  // L2/L3 hit
        const unsigned short* brow = wg + (size_t)nn * D_MODEL + khalf * 8;
        #pragma unroll 4
        for (int kk = 0; kk < 40; ++kk) {
            float4 a0 = *reinterpret_cast<const float4*>(arow + kk * 32);
            float4 a1 = *reinterpret_cast<const float4*>(arow + kk * 32 + 4);
            short8 a;
            a[0] = (short)f2bf(a0.x); a[1] = (short)f2bf(a0.y);
            a[2] = (short)f2bf(a0.z); a[3] = (short)f2bf(a0.w);
            a[4] = (short)f2bf(a1.x); a[5] = (short)f2bf(a1.y);
            a[6] = (short)f2bf(a1.z); a[7] = (short)f2bf(a1.w);
            short8 b = *reinterpret_cast<const short8*>(brow + kk * 32);
            acc = __builtin_amdgcn_mfma_f32_16x16x32_bf16(a, b, acc, 0, 0, 0);
        }
    }

    // ---------------- Phase 3: per-row LN affine + bias + exact GELU -> g_lds -------------
    {
        const float cs  = colsum[nn];
        const float bdn = bd2[nn];
        #pragma unroll
        for (int r = 0; r < 4; ++r) {
            const int m = khalf * 4 + r;   // output row within tile
            const float yv = s_rinv[m] * (acc[r] - s_mean[m] * cs) + bdn;
            const float gv = 0.5f * yv * (1.f + erff(yv * 0.70710678118654752f));
            g_lds[m * GP + nn] = f2bf(gv);
        }
    }
    __syncthreads();

    // ---------------- Phase 4: up-proj (M=16,N=1280,K=64) + bias + residual ---------------
    short8 ga0 = *reinterpret_cast<const short8*>(g_lds + l15 * GP +  0 + khalf * 8);
    short8 ga1 = *reinterpret_cast<const short8*>(g_lds + l15 * GP + 32 + khalf * 8);

    const int m_base = khalf * 4;
    #pragma unroll 4
    for (int i = 0; i < 20; ++i) {
        const int d0 = (i * 4 + wave) * 16;
        const int d  = d0 + l15;
        const unsigned short* bptr = wu_b + (size_t)d * D_BOTTLE + khalf * 8;
        short8 b0 = *reinterpret_cast<const short8*>(bptr);
        short8 b1 = *reinterpret_cast<const short8*>(bptr + 32);
        floatx4 acc2 = {0.f, 0.f, 0.f, 0.f};
        acc2 = __builtin_amdgcn_mfma_f32_16x16x32_bf16(ga0, b0, acc2, 0, 0, 0);
        acc2 = __builtin_amdgcn_mfma_f32_16x16x32_bf16(ga1, b1, acc2, 0, 0, 0);
        const float bu = b_up[d];
        #pragma unroll
        for (int r = 0; r < 4; ++r) {
            const size_t idx = (size_t)(r0 + m_base + r) * D_MODEL + d;
            out[idx] = acc2[r] + bu + x[idx];      // residual: L2/L3 hit
        }
    }
}

extern "C" void kernel_launch(void* const* d_in, const int* in_sizes, int n_in,
                              void* d_out, int out_size, void* d_ws, size_t ws_size,
                              hipStream_t stream) {
    const float* x      = (const float*)d_in[0];
    const float* gamma  = (const float*)d_in[1];
    const float* beta   = (const float*)d_in[2];
    const float* w_down = (const float*)d_in[3];
    const float* b_down = (const float*)d_in[4];
    const float* w_up   = (const float*)d_in[5];
    const float* b_up   = (const float*)d_in[6];
    float* out = (float*)d_out;

    unsigned short* wg   = (unsigned short*)d_ws;                 // 64*1280 bf16
    unsigned short* wu_b = wg + D_MODEL * D_BOTTLE;               // 1280*64 bf16
    float* colsum = (float*)(wu_b + D_MODEL * D_BOTTLE);          // 64 f32
    float* bd2    = colsum + D_BOTTLE;                            // 64 f32

    prep_weights<<<(D_MODEL * D_BOTTLE + 255) / 256, 256, 0, stream>>>(w_down, gamma, w_up, wg, wu_b);
    prep_reduce<<<D_BOTTLE, 256, 0, stream>>>(wg, w_down, beta, b_down, colsum, bd2);

    const int rows = in_sizes[0] / D_MODEL;   // 24000
    adapter_kernel<<<rows / TM, 256, 0, stream>>>(x, wg, colsum, bd2, wu_b, b_up, out);
}

// Round 11
// 317.456 us; speedup vs baseline: 1.0440x; 1.0440x over previous
//
#include <hip/hip_runtime.h>
#include <hip/hip_bf16.h>

#define D_MODEL  1280
#define D_BOTTLE 64
#define LN_EPS   1e-5f
#define TM       8          // rows per block
#define ROWB     2560       // bytes per h_lds row (1280 bf16), exact stride + XOR swizzle
#define GP       72         // g_lds row stride (bf16 elems)

typedef __attribute__((ext_vector_type(8))) short short8;
typedef __attribute__((ext_vector_type(4))) float floatx4;

static __device__ inline unsigned short f2bf(float f) {
    __hip_bfloat16 h = __float2bfloat16(f);
    return *reinterpret_cast<unsigned short*>(&h);
}
static __device__ inline float bf2f(unsigned short u) {
    unsigned int v = ((unsigned int)u) << 16;
    return __uint_as_float(v);
}

// Prep 1: wg = bf16(wd * gamma) [64][1280] ; wu_b = bf16(wu) [1280][64]
__global__ void prep_weights(const float* __restrict__ wd, const float* __restrict__ gamma,
                             const float* __restrict__ wu,
                             unsigned short* __restrict__ wg, unsigned short* __restrict__ wu_b) {
    int i = blockIdx.x * blockDim.x + threadIdx.x;
    if (i < D_MODEL * D_BOTTLE) {
        int k = i % D_MODEL;
        wg[i]   = f2bf(wd[i] * gamma[k]);
        wu_b[i] = f2bf(wu[i]);
    }
}

// Prep 2: colsum[n] = sum_k bf2f(wg[n,k]) ; bd2[n] = b_down[n] + sum_k wd[n,k]*beta[k]
__global__ void prep_reduce(const unsigned short* __restrict__ wg, const float* __restrict__ wd,
                            const float* __restrict__ beta, const float* __restrict__ b_down,
                            float* __restrict__ colsum, float* __restrict__ bd2) {
    const int n = blockIdx.x;
    const int t = threadIdx.x;
    float cs = 0.f, bb = 0.f;
    for (int k = t; k < D_MODEL; k += 256) {
        cs += bf2f(wg[n * D_MODEL + k]);
        bb += wd[n * D_MODEL + k] * beta[k];
    }
    #pragma unroll
    for (int m = 1; m < 64; m <<= 1) {
        cs += __shfl_xor(cs, m);
        bb += __shfl_xor(bb, m);
    }
    __shared__ float scs[4], sbb[4];
    if ((t & 63) == 0) { scs[t >> 6] = cs; sbb[t >> 6] = bb; }
    __syncthreads();
    if (t == 0) {
        colsum[n] = scs[0] + scs[1] + scs[2] + scs[3];
        bd2[n]    = b_down[n] + sbb[0] + sbb[1] + sbb[2] + sbb[3];
    }
}

__global__ __launch_bounds__(256, 6) void adapter_kernel(
    const float* __restrict__ x,
    const unsigned short* __restrict__ wg, const float* __restrict__ colsum,
    const float* __restrict__ bd2,
    const unsigned short* __restrict__ wu_b, const float* __restrict__ b_up,
    float* __restrict__ out)
{
    // h_lds: raw x in bf16, row stride exactly 2560 B, XOR-swizzled: col c of row r
    // lives at byte r*2560 + ((2c) ^ (r<<4)).  -> ds_read_b128 conflict-free.
    __shared__ unsigned char  h_raw[TM * ROWB];     // 20480 B
    __shared__ unsigned short g_lds[TM * GP];       // 1152 B
    __shared__ float s_mean[TM], s_rinv[TM];

    const int tid  = threadIdx.x;
    const int wave = tid >> 6;
    const int lane = tid & 63;
    const int r0   = blockIdx.x * TM;

    // ---------------- Phase 1: load x once -> stats + bf16 LDS stage ----------------
    {
        const int rloc = tid >> 5;        // 0..7 (row), 32 lanes per row
        const int li   = tid & 31;
        const float* xrow = x + (size_t)(r0 + rloc) * D_MODEL;
        float4 v0 = *reinterpret_cast<const float4*>(xrow + li * 4 +    0);
        float4 v1 = *reinterpret_cast<const float4*>(xrow + li * 4 +  128);
        float4 v2 = *reinterpret_cast<const float4*>(xrow + li * 4 +  256);
        float4 v3 = *reinterpret_cast<const float4*>(xrow + li * 4 +  384);
        float4 v4 = *reinterpret_cast<const float4*>(xrow + li * 4 +  512);
        float4 v5 = *reinterpret_cast<const float4*>(xrow + li * 4 +  640);
        float4 v6 = *reinterpret_cast<const float4*>(xrow + li * 4 +  768);
        float4 v7 = *reinterpret_cast<const float4*>(xrow + li * 4 +  896);
        float4 v8 = *reinterpret_cast<const float4*>(xrow + li * 4 + 1024);
        float4 v9 = *reinterpret_cast<const float4*>(xrow + li * 4 + 1152);

        float s = 0.f, sq = 0.f;
        #define ACC4(v) { s += v.x + v.y + v.z + v.w; sq += v.x*v.x + v.y*v.y + v.z*v.z + v.w*v.w; }
        ACC4(v0) ACC4(v1) ACC4(v2) ACC4(v3) ACC4(v4)
        ACC4(v5) ACC4(v6) ACC4(v7) ACC4(v8) ACC4(v9)
        #undef ACC4
        #pragma unroll
        for (int m = 1; m < 32; m <<= 1) {
            s  += __shfl_xor(s, m);
            sq += __shfl_xor(sq, m);
        }
        const float mean = s * (1.f / D_MODEL);
        const float var  = sq * (1.f / D_MODEL) - mean * mean;
        if (li == 0) { s_mean[rloc] = mean; s_rinv[rloc] = rsqrtf(var + LN_EPS); }

        const int swz = rloc << 4;
        #define ST4(v, t) { ushort4 pk; pk.x = f2bf(v.x); pk.y = f2bf(v.y); pk.z = f2bf(v.z); pk.w = f2bf(v.w); \
            *reinterpret_cast<ushort4*>(h_raw + rloc * ROWB + ((li * 8 + 256 * (t)) ^ swz)) = pk; }
        ST4(v0,0) ST4(v1,1) ST4(v2,2) ST4(v3,3) ST4(v4,4)
        ST4(v5,5) ST4(v6,6) ST4(v7,7) ST4(v8,8) ST4(v9,9)
        #undef ST4
    }
    __syncthreads();

    // ---------------- Phase 2: down-proj (M=8 in 16x16 MFMA, N=64, K=1280) ----------
    const int l15   = lane & 15;
    const int khalf = lane >> 4;        // 0..3
    const int lr    = l15 & 7;          // LDS row (rows 8-15 duplicate 0-7)
    const int nn    = wave * 16 + l15;  // bottleneck channel

    floatx4 acc = {0.f, 0.f, 0.f, 0.f};
    {
        const unsigned short* brow = wg + (size_t)nn * D_MODEL + khalf * 8;
        const unsigned char*  abase = h_raw + lr * ROWB;
        const int aswz = lr << 4;
        #pragma unroll 4
        for (int kk = 0; kk < 40; ++kk) {
            short8 a = *reinterpret_cast<const short8*>(abase + ((kk * 64 + khalf * 16) ^ aswz));
            short8 b = *reinterpret_cast<const short8*>(brow + kk * 32);
            acc = __builtin_amdgcn_mfma_f32_16x16x32_bf16(a, b, acc, 0, 0, 0);
        }
    }

    // ---------------- Phase 3: LN affine + bias + exact GELU -> g_lds ----------------
    {
        const float cs  = colsum[nn];
        const float bdn = bd2[nn];
        if (khalf < 2) {
            #pragma unroll
            for (int r = 0; r < 4; ++r) {
                const int m = khalf * 4 + r;      // 0..7
                const float yv = s_rinv[m] * (acc[r] - s_mean[m] * cs) + bdn;
                const float gv = 0.5f * yv * (1.f + erff(yv * 0.70710678118654752f));
                g_lds[m * GP + nn] = f2bf(gv);
            }
        }
    }
    __syncthreads();

    // ---------------- Phase 4: up-proj (M=8, N=1280, K=64) + bias + residual --------
    short8 ga0 = *reinterpret_cast<const short8*>(g_lds + lr * GP +  0 + khalf * 8);
    short8 ga1 = *reinterpret_cast<const short8*>(g_lds + lr * GP + 32 + khalf * 8);

    #pragma unroll 2
    for (int i = 0; i < 20; ++i) {
        const int d = (i * 4 + wave) * 16 + l15;
        const unsigned short* bptr = wu_b + (size_t)d * D_BOTTLE + khalf * 8;
        short8 b0 = *reinterpret_cast<const short8*>(bptr);
        short8 b1 = *reinterpret_cast<const short8*>(bptr + 32);
        floatx4 acc2 = {0.f, 0.f, 0.f, 0.f};
        acc2 = __builtin_amdgcn_mfma_f32_16x16x32_bf16(ga0, b0, acc2, 0, 0, 0);
        acc2 = __builtin_amdgcn_mfma_f32_16x16x32_bf16(ga1, b1, acc2, 0, 0, 0);
        const float bu = b_up[d];
        if (khalf < 2) {
            #pragma unroll
            for (int r = 0; r < 4; ++r) {
                const int m = khalf * 4 + r;      // 0..7
                // residual from bf16-staged x (no global re-read)
                const unsigned short xr16 =
                    *reinterpret_cast<const unsigned short*>(h_raw + m * ROWB + ((d * 2) ^ (m << 4)));
                out[(size_t)(r0 + m) * D_MODEL + d] = acc2[r] + bu + bf2f(xr16);
            }
        }
    }
}

extern "C" void kernel_launch(void* const* d_in, const int* in_sizes, int n_in,
                              void* d_out, int out_size, void* d_ws, size_t ws_size,
                              hipStream_t stream) {
    const float* x      = (const float*)d_in[0];
    const float* gamma  = (const float*)d_in[1];
    const float* beta   = (const float*)d_in[2];
    const float* w_down = (const float*)d_in[3];
    const float* b_down = (const float*)d_in[4];
    const float* w_up   = (const float*)d_in[5];
    const float* b_up   = (const float*)d_in[6];
    float* out = (float*)d_out;

    unsigned short* wg   = (unsigned short*)d_ws;                 // 64*1280 bf16
    unsigned short* wu_b = wg + D_MODEL * D_BOTTLE;               // 1280*64 bf16
    float* colsum = (float*)(wu_b + D_MODEL * D_BOTTLE);          // 64 f32
    float* bd2    = colsum + D_BOTTLE;                            // 64 f32

    prep_weights<<<(D_MODEL * D_BOTTLE + 255) / 256, 256, 0, stream>>>(w_down, gamma, w_up, wg, wu_b);
    prep_reduce<<<D_BOTTLE, 256, 0, stream>>>(wg, w_down, beta, b_down, colsum, bd2);

    const int rows = in_sizes[0] / D_MODEL;   // 24000
    adapter_kernel<<<rows / TM, 256, 0, stream>>>(x, wg, colsum, bd2, wu_b, b_up, out);
}